// Round 1
// 90.783 us; speedup vs baseline: 1.0254x; 1.0254x over previous
//
#include <hip/hip_runtime.h>
#include <hip/hip_bf16.h>

// Problem constants: B=16, TV=128, TH=64, F=512, H=512, D=256
#define BB 16
#define TV 128
#define TH 64
#define FF 512
#define HH 512
#define DD 256

#define LOG2E2 2.8853900817779268f   // 2*log2(e): exp2(LOG2E2*x) = e^{2x}

typedef __attribute__((ext_vector_type(8))) short bf16x8;   // 8 bf16 = 4 VGPRs
typedef __attribute__((ext_vector_type(4))) float f32x4;

__device__ __forceinline__ float fast_exp2(float x) {
#if __has_builtin(__builtin_amdgcn_exp2f)
  return __builtin_amdgcn_exp2f(x);
#else
  return __expf(x * 0.6931471805599453f);
#endif
}
__device__ __forceinline__ float fast_rcp(float x) {
#if __has_builtin(__builtin_amdgcn_rcpf)
  return __builtin_amdgcn_rcpf(x);
#else
  return 1.0f / x;
#endif
}
__device__ __forceinline__ unsigned short f2bf(float x) {  // RNE fp32->bf16
  union { float f; unsigned u; } a; a.f = x;
  unsigned r = a.u + 0x7fffu + ((a.u >> 16) & 1u);
  return (unsigned short)(r >> 16);
}

// ---------------------------------------------------------------------------
// Convert kernel: v,h -> bf16 (row-major); W,U -> bf16 TRANSPOSED ([n][k]).
// ---------------------------------------------------------------------------
#define NT_V 262144
#define NT_H 131072
#define NT_W 32768
__global__ __launch_bounds__(256) void convert_kernel(
    const float* __restrict__ v, const float* __restrict__ h,
    const float* __restrict__ W, const float* __restrict__ U,
    unsigned short* __restrict__ vb, unsigned short* __restrict__ hb,
    unsigned short* __restrict__ WT, unsigned short* __restrict__ UT) {
  int task = blockIdx.x * 256 + threadIdx.x;
  if (task < NT_V) {
    float4 x = ((const float4*)v)[task];
    ushort4 o = make_ushort4(f2bf(x.x), f2bf(x.y), f2bf(x.z), f2bf(x.w));
    *(ushort4*)&vb[(size_t)task * 4] = o;
  } else if (task < NT_V + NT_H) {
    int t2 = task - NT_V;
    float4 x = ((const float4*)h)[t2];
    ushort4 o = make_ushort4(f2bf(x.x), f2bf(x.y), f2bf(x.z), f2bf(x.w));
    *(ushort4*)&hb[(size_t)t2 * 4] = o;
  } else {
    int t2 = task - NT_V - NT_H;
    const float* S;
    unsigned short* Dt;
    if (t2 < NT_W) { S = W; Dt = WT; } else { S = U; Dt = UT; t2 -= NT_W; }
    int n = t2 & 255, k4 = t2 >> 8;           // k4 in [0,128)
    float a0 = S[(k4 * 4 + 0) * 256 + n];     // coalesced over n
    float a1 = S[(k4 * 4 + 1) * 256 + n];
    float a2 = S[(k4 * 4 + 2) * 256 + n];
    float a3 = S[(k4 * 4 + 3) * 256 + n];
    ushort4 o = make_ushort4(f2bf(a0), f2bf(a1), f2bf(a2), f2bf(a3));
    *(ushort4*)&Dt[(size_t)n * 512 + k4 * 4] = o;
  }
}

// ---------------------------------------------------------------------------
// MFMA GEMM, no LDS, no barriers. 384 blocks * 128 thr (2 waves).
//   blocks [0,256):   EaT[b][d][t]  = exp2(LOG2E2 * (v @ W))   (TRANSPOSED)
//   blocks [256,384): EuhT[m][d]    = exp2(LOG2E2 * (h @ U + b))
// exp2 HOISTED here (0.5M evals) out of the attn score loop (was 33.5M):
// e^{2(Wv+Uh+b)} = e^{2Wv} * e^{2(Uh+b)}.
// Wave tile: 32m x 32n x 512k via 2x2 of mfma_f32_16x16x32_bf16.
// C/D: col = l&15, row = (l>>4)*4 + reg   (m89-verified)
// ---------------------------------------------------------------------------
__global__ __launch_bounds__(128) void mfma_gemm_kernel(
    const unsigned short* __restrict__ Av, const unsigned short* __restrict__ Ah,
    const unsigned short* __restrict__ WT, const unsigned short* __restrict__ UT,
    const float* __restrict__ bias, float* __restrict__ EaT,
    float* __restrict__ EuhT) {
  const int bid = blockIdx.x;
  const unsigned short* A;
  const unsigned short* BT;
  int mt, nt;
  bool is_wv;
  if (bid < 256) {
    A = Av; BT = WT; is_wv = true;
    mt = bid >> 3; nt = bid & 7;
  } else {
    const int b2 = bid - 256;
    A = Ah; BT = UT; is_wv = false;
    mt = b2 >> 3; nt = b2 & 7;
  }
  const int wv   = threadIdx.x >> 6;   // 0..1
  const int lane = threadIdx.x & 63;
  const int m0   = mt * 64 + wv * 32;
  const int n0   = nt * 32;
  const int r16  = lane & 15;
  const int quad = lane >> 4;

  const unsigned short* a0p = A + (size_t)(m0 + r16) * 512 + quad * 8;
  const unsigned short* a1p = a0p + 16 * 512;
  const unsigned short* b0p = BT + (size_t)(n0 + r16) * 512 + quad * 8;
  const unsigned short* b1p = b0p + 16 * 512;

  f32x4 acc00 = {0.f, 0.f, 0.f, 0.f};
  f32x4 acc01 = {0.f, 0.f, 0.f, 0.f};
  f32x4 acc10 = {0.f, 0.f, 0.f, 0.f};
  f32x4 acc11 = {0.f, 0.f, 0.f, 0.f};

#pragma unroll
  for (int kc = 0; kc < 16; kc++) {
    bf16x8 a0 = *(const bf16x8*)(a0p + kc * 32);
    bf16x8 a1 = *(const bf16x8*)(a1p + kc * 32);
    bf16x8 b0 = *(const bf16x8*)(b0p + kc * 32);
    bf16x8 b1 = *(const bf16x8*)(b1p + kc * 32);
    acc00 = __builtin_amdgcn_mfma_f32_16x16x32_bf16(a0, b0, acc00, 0, 0, 0);
    acc01 = __builtin_amdgcn_mfma_f32_16x16x32_bf16(a0, b1, acc01, 0, 0, 0);
    acc10 = __builtin_amdgcn_mfma_f32_16x16x32_bf16(a1, b0, acc10, 0, 0, 0);
    acc11 = __builtin_amdgcn_mfma_f32_16x16x32_bf16(a1, b1, acc11, 0, 0, 0);
  }

  if (is_wv) {
    // transposed store: EaT[b*32768 + d*128 + t], d = n-col, t = m&127
    const int bb   = m0 >> 7;
    const int tb   = (m0 & 127) + quad * 4;       // + r below
    float* Wb = EaT + (size_t)bb * 32768;
#pragma unroll
    for (int r = 0; r < 4; r++) {
      Wb[(size_t)(n0 + r16) * 128 + tb + r]           = fast_exp2(acc00[r] * LOG2E2);
      Wb[(size_t)(n0 + 16 + r16) * 128 + tb + r]      = fast_exp2(acc01[r] * LOG2E2);
      Wb[(size_t)(n0 + r16) * 128 + tb + 16 + r]      = fast_exp2(acc10[r] * LOG2E2);
      Wb[(size_t)(n0 + 16 + r16) * 128 + tb + 16 + r] = fast_exp2(acc11[r] * LOG2E2);
    }
  } else {
    const float bj0 = bias[n0 + r16];
    const float bj1 = bias[n0 + 16 + r16];
#pragma unroll
    for (int r = 0; r < 4; r++) {
      const int row0 = m0 + quad * 4 + r;
      EuhT[(size_t)row0 * 256 + n0 + r16]             = fast_exp2((acc00[r] + bj0) * LOG2E2);
      EuhT[(size_t)row0 * 256 + n0 + 16 + r16]        = fast_exp2((acc01[r] + bj1) * LOG2E2);
      EuhT[(size_t)(row0 + 16) * 256 + n0 + r16]      = fast_exp2((acc10[r] + bj0) * LOG2E2);
      EuhT[(size_t)(row0 + 16) * 256 + n0 + 16 + r16] = fast_exp2((acc11[r] + bj1) * LOG2E2);
    }
  }
}

// ---------------------------------------------------------------------------
// Fused attention. 256 blocks, 1024 thr. XCD-swizzled so all 16 sg-blocks of
// a batch b land on one XCD (v[b]+EaT[b] become XCD-L2-resident).
// Score: thread = (dgf:32, t4:32). Each thread owns 8 d's, 4 t's, ALL 4 s's:
//   Ea float4 loaded ONCE and reused for 4 s (was 4x redundant loads).
//   sigmoid denominators D = 1 + Ea*Euh (exp2 pre-hoisted into GEMM).
//   Pairwise rcp merge: w0/D0 + w1/D1 = (w0*D1+w1*D0)/(D0*D1) -> rcps halved.
//   Cross-dgf: shfl_xor(32) pairs dgf 2w/2w+1, then pS[4][16][128] in LDS.
// Softmax over t: threads<512, wave shuffle + 2-wave LDS combine.
// Context: thread = (f:512, sh:2), coalesced v reads, broadcast beta.
// ---------------------------------------------------------------------------
__global__ __launch_bounds__(1024) void attn_fused_kernel(
    const float* __restrict__ EaT, const float* __restrict__ EuhT,
    const float* __restrict__ wg, const float* __restrict__ v,
    float* __restrict__ u) {
  __shared__ float EuhS[4 * 256];
  __shared__ float wS[256];
  __shared__ float pS[4 * 16 * 128];   // [s][wavepair][t]
  __shared__ float bS[4 * 128];
  __shared__ float mW[8];
  __shared__ float sW[8];

  const int tid = threadIdx.x;
  // bijective XCD swizzle: round-robin dispatch puts bid&7 on XCD (bid&7);
  // give each XCD 2 full b's (16 sg-blocks each).
  const int bid  = blockIdx.x;
  const int slot = bid >> 3;
  const int b    = (bid & 7) * 2 + (slot >> 4);
  const int sg   = slot & 15;
  const int s0   = sg * 4;

  // ---- stage Euh (4x256, already exp2'd) and w (256) ----
  if (tid < 256) {
    const int row = tid >> 6, q4 = (tid & 63) << 2;
    *(float4*)&EuhS[row * 256 + q4] =
        *(const float4*)&EuhT[(size_t)(b * 64 + s0 + row) * 256 + q4];
  } else if (tid < 320) {
    const int q4 = (tid - 256) << 2;
    *(float4*)&wS[q4] = *(const float4*)&wg[q4];
  }
  __syncthreads();

  // ---- scores: thread = (dgf, t4); 8 d x 4 t x 4 s each ----
  {
    const int t4  = tid & 31;
    const int dgf = tid >> 5;                     // 0..31
    const float* eab = EaT + (size_t)b * 32768 + (size_t)dgf * 8 * 128 + t4 * 4;

    // preload Euh (4s x 8d) and w (8d) into registers (static-indexed)
    float eu[4][8];
    float wr[8];
#pragma unroll
    for (int s = 0; s < 4; s++) {
      *(float4*)&eu[s][0] = *(const float4*)&EuhS[s * 256 + dgf * 8];
      *(float4*)&eu[s][4] = *(const float4*)&EuhS[s * 256 + dgf * 8 + 4];
    }
    *(float4*)&wr[0] = *(const float4*)&wS[dgf * 8];
    *(float4*)&wr[4] = *(const float4*)&wS[dgf * 8 + 4];

    f32x4 acc[4];
#pragma unroll
    for (int s = 0; s < 4; s++) acc[s] = (f32x4){0.f, 0.f, 0.f, 0.f};

#pragma unroll
    for (int jp = 0; jp < 4; jp++) {            // 4 d-pairs
      float4 e0 = *(const float4*)(eab + (2 * jp + 0) * 128);
      float4 e1 = *(const float4*)(eab + (2 * jp + 1) * 128);
      const float w0 = wr[2 * jp], w1 = wr[2 * jp + 1];
#pragma unroll
      for (int s = 0; s < 4; s++) {
        const float u0 = eu[s][2 * jp], u1 = eu[s][2 * jp + 1];
        float D0, D1, num;
        D0 = fmaf(e0.x, u0, 1.0f); D1 = fmaf(e1.x, u1, 1.0f);
        num = fmaf(w1, D0, w0 * D1);
        acc[s][0] = fmaf(num, fast_rcp(D0 * D1), acc[s][0]);
        D0 = fmaf(e0.y, u0, 1.0f); D1 = fmaf(e1.y, u1, 1.0f);
        num = fmaf(w1, D0, w0 * D1);
        acc[s][1] = fmaf(num, fast_rcp(D0 * D1), acc[s][1]);
        D0 = fmaf(e0.z, u0, 1.0f); D1 = fmaf(e1.z, u1, 1.0f);
        num = fmaf(w1, D0, w0 * D1);
        acc[s][2] = fmaf(num, fast_rcp(D0 * D1), acc[s][2]);
        D0 = fmaf(e0.w, u0, 1.0f); D1 = fmaf(e1.w, u1, 1.0f);
        num = fmaf(w1, D0, w0 * D1);
        acc[s][3] = fmaf(num, fast_rcp(D0 * D1), acc[s][3]);
      }
    }

    // combine dgf pair (2w, 2w+1): lane l += lane l^32
#pragma unroll
    for (int s = 0; s < 4; s++) {
#pragma unroll
      for (int c = 0; c < 4; c++) acc[s][c] += __shfl_xor(acc[s][c], 32, 64);
    }
    const int wv_ = tid >> 6;                   // 0..15
    if ((tid & 63) < 32) {
#pragma unroll
      for (int s = 0; s < 4; s++) {
        float4 o = make_float4(acc[s][0], acc[s][1], acc[s][2], acc[s][3]);
        *(float4*)&pS[(s * 16 + wv_) * 128 + t4 * 4] = o;
      }
    }
  }
  __syncthreads();

  // ---- reduce over 16 wavepairs + softmax over t (threads < 512) ----
  float qv = 0.0f, ev = 0.0f;
  const int wvid = tid >> 6, lane = tid & 63;
  if (tid < 512) {
    const int s_l = tid >> 7, t = tid & 127;
    float ssum = 0.0f;
#pragma unroll
    for (int k = 0; k < 16; k++) ssum += pS[(s_l * 16 + k) * 128 + t];
    qv = ssum * (-LOG2E2);   // log2-domain score
    float m = qv;
#pragma unroll
    for (int off = 32; off > 0; off >>= 1) m = fmaxf(m, __shfl_xor(m, off, 64));
    if (lane == 0) mW[wvid] = m;
  }
  __syncthreads();
  if (tid < 512) {
    float m = fmaxf(mW[wvid], mW[wvid ^ 1]);
    ev = fast_exp2(qv - m);
    float ssum = ev;
#pragma unroll
    for (int off = 32; off > 0; off >>= 1) ssum += __shfl_xor(ssum, off, 64);
    if (lane == 0) sW[wvid] = ssum;
  }
  __syncthreads();
  if (tid < 512) {
    const int s_l = tid >> 7, t = tid & 127;
    bS[s_l * 128 + t] = ev * fast_rcp(sW[wvid] + sW[wvid ^ 1]);
  }
  __syncthreads();

  // ---- context: thread = (f:512, sh:2); 2 s-rows each ----
  const float* vb2 = v + (size_t)b * TV * FF;
  const int f  = tid & 511;
  const int sh = tid >> 9;
  float a0 = 0.f, a1 = 0.f;
#pragma unroll 4
  for (int tg = 0; tg < 128; tg += 4) {
    float4 b0 = *(const float4*)&bS[(sh * 2 + 0) * 128 + tg];
    float4 b1 = *(const float4*)&bS[(sh * 2 + 1) * 128 + tg];
    float v0 = vb2[(tg + 0) * 512 + f];
    float v1 = vb2[(tg + 1) * 512 + f];
    float v2 = vb2[(tg + 2) * 512 + f];
    float v3 = vb2[(tg + 3) * 512 + f];
    a0 = fmaf(b0.x, v0, a0); a0 = fmaf(b0.y, v1, a0);
    a0 = fmaf(b0.z, v2, a0); a0 = fmaf(b0.w, v3, a0);
    a1 = fmaf(b1.x, v0, a1); a1 = fmaf(b1.y, v1, a1);
    a1 = fmaf(b1.z, v2, a1); a1 = fmaf(b1.w, v3, a1);
  }
  float* urow = u + (size_t)(b * 64 + s0 + sh * 2) * 512;
  urow[0 * 512 + f] = a0;
  urow[1 * 512 + f] = a1;
}

extern "C" void kernel_launch(void* const* d_in, const int* in_sizes, int n_in,
                              void* d_out, int out_size, void* d_ws, size_t ws_size,
                              hipStream_t stream) {
  const float* v  = (const float*)d_in[0];  // [16,128,512]
  const float* h  = (const float*)d_in[1];  // [16,64,512]
  const float* W  = (const float*)d_in[2];  // [512,256]
  const float* U  = (const float*)d_in[3];  // [512,256]
  const float* bb = (const float*)d_in[4];  // [256]
  const float* w  = (const float*)d_in[5];  // [256,1]
  float* u = (float*)d_out;                 // [16,64,512]

  float* EaT  = (float*)d_ws;                      // [16][256][128] f32 = exp2(2Wv*log2e)
  float* EuhT = EaT + (size_t)2048 * 256;          // [1024,256] f32 = exp2(2(Uh+b)*log2e)
  unsigned short* vb16 = (unsigned short*)(EuhT + (size_t)1024 * 256);
  unsigned short* hb16 = vb16 + (size_t)2048 * 512;  // bf16 copies
  unsigned short* WT   = hb16 + (size_t)1024 * 512;  // [256][512] bf16 (W^T)
  unsigned short* UT   = WT + (size_t)256 * 512;     // [256][512] bf16 (U^T)

  convert_kernel<<<1792, 256, 0, stream>>>(v, h, W, U, vb16, hb16, WT, UT);
  mfma_gemm_kernel<<<384, 128, 0, stream>>>(vb16, hb16, WT, UT, bb, EaT, EuhT);
  attn_fused_kernel<<<256, 1024, 0, stream>>>(EaT, EuhT, w, v, u);
}